// Round 8
// baseline (73.251 us; speedup 1.0000x reference)
//
#include <hip/hip_runtime.h>
#include <hip/hip_bf16.h>

typedef __attribute__((ext_vector_type(8))) short short8;
typedef __attribute__((ext_vector_type(4))) float f32x4;
typedef __attribute__((ext_vector_type(4))) unsigned short ushort4v;
typedef unsigned short u16;

#define MFMA32(a, b, c) __builtin_amdgcn_mfma_f32_16x16x32_bf16((a), (b), (c), 0, 0, 0)

__device__ __forceinline__ u16 f2bf(float f) {
    union { float f; unsigned int u; } v; v.f = f;
    unsigned int r = v.u + 0x7FFFu + ((v.u >> 16) & 1u);   // RNE
    return (u16)(r >> 16);
}

// Rolled flash attention for one 16-row t-tile (verified R7). Mask ring is
// depth-2: pm = chunk c (arrived >=2 iters ago), nm = chunk c+1 (in flight),
// fut = chunk c+2 (issued here). First two chunks preloaded by the caller
// BEFORE the projection phase (latency hidden under ~10K cycles of GEMM).
__device__ __forceinline__ void do_tile(int Tb, int nst, int lr, int lg,
                                        const short8* qf,           // [2]
                                        const u16 (*lk)[72],
                                        const u16 (*lvT)[264],
                                        u16* pbw,                   // wave-private [16][40]
                                        const float* mb, float* ob,
                                        float pm[2][4], float nm[2][4])
{
    const int tb = Tb + 4 * lg;
    float m[4], ls[4];
    f32x4 O[4];
    #pragma unroll
    for (int j = 0; j < 4; ++j) { m[j] = -1e30f; ls[j] = 0.f; }
    #pragma unroll
    for (int ht = 0; ht < 4; ++ht) O[ht] = (f32x4){0.f, 0.f, 0.f, 0.f};

    #pragma unroll 1
    for (int c = 0; 2 * c < nst; ++c) {
        // ---- issue chunk c+2's dropout-mask loads (depth-2 slack ~2 iters) ----
        float fut[2][4];
        #pragma unroll
        for (int sl = 0; sl < 2; ++sl) {
            const int stn = 2 * c + 4 + sl;
            #pragma unroll
            for (int j = 0; j < 4; ++j) fut[sl][j] = 0.f;
            if (stn < nst) {
                #pragma unroll
                for (int j = 0; j < 4; ++j)
                    fut[sl][j] = mb[(size_t)(tb + j) * 256 + 16 * stn + lr];
            }
        }

        // ---- QK^T for s-tiles 2c, 2c+1 ----
        // odd-tail subtile is causally dead -> masked to 0 below; row < 256 always.
        f32x4 S[2];
        #pragma unroll
        for (int sl = 0; sl < 2; ++sl) {
            const u16* kr = &lk[16 * (2 * c + sl) + lr][0];
            ushort4v t0 = *(const ushort4v*)&kr[4 * lg];
            ushort4v t1 = *(const ushort4v*)&kr[16 + 4 * lg];
            ushort4v t2 = *(const ushort4v*)&kr[32 + 4 * lg];
            ushort4v t3 = *(const ushort4v*)&kr[48 + 4 * lg];
            short8 kf0, kf1;
            kf0[0]=(short)t0[0]; kf0[1]=(short)t0[1]; kf0[2]=(short)t0[2]; kf0[3]=(short)t0[3];
            kf0[4]=(short)t1[0]; kf0[5]=(short)t1[1]; kf0[6]=(short)t1[2]; kf0[7]=(short)t1[3];
            kf1[0]=(short)t2[0]; kf1[1]=(short)t2[1]; kf1[2]=(short)t2[2]; kf1[3]=(short)t2[3];
            kf1[4]=(short)t3[0]; kf1[5]=(short)t3[1]; kf1[6]=(short)t3[2]; kf1[7]=(short)t3[3];
            f32x4 a = (f32x4){0.f, 0.f, 0.f, 0.f};
            a = MFMA32(qf[0], kf0, a);
            a = MFMA32(qf[1], kf1, a);
            S[sl] = a;
        }

        // ---- scale + causal mask + chunk max ----
        float cm[4];
        #pragma unroll
        for (int j = 0; j < 4; ++j) cm[j] = m[j];
        #pragma unroll
        for (int sl = 0; sl < 2; ++sl) {
            const int s = 16 * (2 * c + sl) + lr;
            #pragma unroll
            for (int j = 0; j < 4; ++j) {
                float Lv = (s <= tb + j) ? S[sl][j] * 0.125f : -1e30f;
                S[sl][j] = Lv;
                cm[j] = fmaxf(cm[j], Lv);
            }
        }
        #pragma unroll
        for (int d = 1; d < 16; d <<= 1)
            #pragma unroll
            for (int j = 0; j < 4; ++j)
                cm[j] = fmaxf(cm[j], __shfl_xor(cm[j], d, 64));

        // ---- rescale running state (fs == 0 on first chunk since m = -1e30) ----
        float fs[4];
        #pragma unroll
        for (int j = 0; j < 4; ++j)
            fs[j] = exp2f((m[j] - cm[j]) * 1.44269504f);
        {
            float fsel = (lr & 3) == 0 ? fs[0] : (lr & 3) == 1 ? fs[1]
                       : (lr & 3) == 2 ? fs[2] : fs[3];
            float fO = __shfl(fsel, ((lr >> 2) << 4) | lr, 64);
            #pragma unroll
            for (int ht = 0; ht < 4; ++ht) O[ht] *= fO;
        }
        #pragma unroll
        for (int j = 0; j < 4; ++j) m[j] = cm[j];

        // ---- exp + chunk sum ----
        float cs[4] = {0.f, 0.f, 0.f, 0.f};
        #pragma unroll
        for (int sl = 0; sl < 2; ++sl)
            #pragma unroll
            for (int j = 0; j < 4; ++j) {
                float p = exp2f((S[sl][j] - m[j]) * 1.44269504f);
                S[sl][j] = p;
                cs[j] += p;
            }
        #pragma unroll
        for (int d = 1; d < 16; d <<= 1)
            #pragma unroll
            for (int j = 0; j < 4; ++j)
                cs[j] += __shfl_xor(cs[j], d, 64);
        #pragma unroll
        for (int j = 0; j < 4; ++j)
            ls[j] = ls[j] * fs[j] + cs[j];

        // ---- dropout (mask arrived >=2 iters ago) + pack -> wave-private P^T ----
        #pragma unroll
        for (int sl = 0; sl < 2; ++sl)
            #pragma unroll
            for (int j = 0; j < 4; ++j) {
                float p = (pm[sl][j] >= 0.25f) ? S[sl][j] : 0.f;
                pbw[(4 * lg + j) * 40 + 16 * sl + lr] = f2bf(p);
            }
        asm volatile("s_waitcnt lgkmcnt(0)" ::: "memory");
        __builtin_amdgcn_sched_barrier(0);
        short8 pf = *(const short8*)&pbw[lr * 40 + 8 * lg];
        #pragma unroll
        for (int ht = 0; ht < 4; ++ht) {
            short8 vf = *(const short8*)&lvT[16 * ht + lr][32 * c + 8 * lg];
            O[ht] = MFMA32(vf, pf, O[ht]);
        }

        // ---- roll the mask ring ----
        #pragma unroll
        for (int sl = 0; sl < 2; ++sl)
            #pragma unroll
            for (int j = 0; j < 4; ++j) {
                pm[sl][j] = nm[sl][j];
                nm[sl][j] = fut[sl][j];
            }
    }

    // ---- final normalize + store ----
    float rs[4];
    #pragma unroll
    for (int j = 0; j < 4; ++j)
        rs[j] = 1.33333333333f / ls[j];     // (1/sum) * 1/(1-0.25)
    float rsel = (lr & 3) == 0 ? rs[0] : (lr & 3) == 1 ? rs[1]
               : (lr & 3) == 2 ? rs[2] : rs[3];
    float rfin = __shfl(rsel, ((lr >> 2) << 4) | lr, 64);
    #pragma unroll
    for (int ht = 0; ht < 4; ++ht) {
        f32x4 o = O[ht] * rfin;
        *(f32x4*)&ob[(size_t)(Tb + lr) * 64 + 16 * ht + 4 * lg] = o;
    }
}

// stage full W^T bf16 into wt: lane l owns row n=l; wave w owns chunks 8(w+8i)
#define STAGE_W(Wm) do {                                                     \
    _Pragma("unroll")                                                        \
    for (int i_ = 0; i_ < 4; ++i_) {                                         \
        const int c0_ = 8 * (w + 8 * i_);                                    \
        short8 t_;                                                           \
        _Pragma("unroll")                                                    \
        for (int j_ = 0; j_ < 8; ++j_)                                       \
            t_[j_] = (short)f2bf((Wm)[(size_t)(c0_ + j_) * 64 + l]);         \
        *(short8*)&wt[l][c0_] = t_;                                          \
    } } while (0)

// One workgroup per batch; 8 waves; wave w owns t-tiles {w, 15-w} (balanced).
// Full W^T staging; attention barrier-free. LDS = 114688 B -> 1 block/CU;
// launch_bounds(512,2) -> 256-reg budget. Mask chunks 0/1 of BOTH tiles are
// pre-issued before the projections (arrive during ~10K cycles of GEMM).
__global__ __launch_bounds__(512, 2)
void attn_head_fused(const float* __restrict__ x,
                     const float* __restrict__ Wq,
                     const float* __restrict__ Wk,
                     const float* __restrict__ Wv,
                     const float* __restrict__ dmask,
                     float* __restrict__ out)
{
    __shared__ __align__(16) u16 lk[256][72];       // k [s][h]    36864 B
    __shared__ __align__(16) u16 lvT[64][264];      // v^T [h][s]  33792 B
    __shared__ __align__(16) u16 wt[64][264];       // W^T [n][c]  33792 B
    __shared__ __align__(16) u16 pb[8][16][40];     // per-wave P^T 10240 B

    const int b   = blockIdx.x;
    const int tid = threadIdx.x;
    const int w   = tid >> 6;
    const int l   = tid & 63;
    const int lr  = l & 15;
    const int lg  = l >> 4;

    const int TbA = 16 * w;
    const int TbB = 16 * (15 - w);
    const int nst0 = w + 1;
    const int nst1 = 16 - w;

    const float* xb = x + (size_t)b * (256 * 256);
    const float* mb = dmask + (size_t)b * (256 * 256);

    // ---- pre-issue mask chunks 0/1 for BOTH tiles (consumed after projections) ----
    float mA[2][2][4], mB[2][2][4];   // [chunk][subtile][j]
    #pragma unroll
    for (int ch = 0; ch < 2; ++ch)
        #pragma unroll
        for (int sl = 0; sl < 2; ++sl) {
            const int st = 2 * ch + sl;
            #pragma unroll
            for (int j = 0; j < 4; ++j) { mA[ch][sl][j] = 0.f; mB[ch][sl][j] = 0.f; }
            if (st < nst0) {
                #pragma unroll
                for (int j = 0; j < 4; ++j)
                    mA[ch][sl][j] = mb[(size_t)(TbA + 4 * lg + j) * 256 + 16 * st + lr];
            }
            if (st < nst1) {
                #pragma unroll
                for (int j = 0; j < 4; ++j)
                    mB[ch][sl][j] = mb[(size_t)(TbB + 4 * lg + j) * 256 + 16 * st + lr];
            }
        }

    // ---- x A-fragments for both tiles (reused by all three projections) ----
    short8 af[2][8];
    #pragma unroll
    for (int ti = 0; ti < 2; ++ti) {
        const float* xr = xb + (size_t)((ti ? TbB : TbA) + lr) * 256 + lg * 8;
        #pragma unroll
        for (int ks = 0; ks < 8; ++ks) {
            f32x4 a0 = *(const f32x4*)(xr + ks * 32);
            f32x4 a1 = *(const f32x4*)(xr + ks * 32 + 4);
            short8 f;
            f[0] = (short)f2bf(a0[0]); f[1] = (short)f2bf(a0[1]);
            f[2] = (short)f2bf(a0[2]); f[3] = (short)f2bf(a0[3]);
            f[4] = (short)f2bf(a1[0]); f[5] = (short)f2bf(a1[1]);
            f[6] = (short)f2bf(a1[2]); f[7] = (short)f2bf(a1[3]);
            af[ti][ks] = f;
        }
    }

    f32x4 acc[2][4];

    // ================= k projection =================
    STAGE_W(Wk);
    __syncthreads();                                   // B1
    #pragma unroll
    for (int ti = 0; ti < 2; ++ti)
        #pragma unroll
        for (int nj = 0; nj < 4; ++nj) acc[ti][nj] = (f32x4){0.f,0.f,0.f,0.f};
    #pragma unroll
    for (int ks = 0; ks < 8; ++ks)
        #pragma unroll
        for (int nj = 0; nj < 4; ++nj) {
            short8 bf = *(const short8*)&wt[16 * nj + lr][ks * 32 + lg * 8];
            acc[0][nj] = MFMA32(af[0][ks], bf, acc[0][nj]);
            acc[1][nj] = MFMA32(af[1][ks], bf, acc[1][nj]);
        }
    #pragma unroll
    for (int nj = 0; nj < 4; ++nj) {
        const int n = 16 * nj + lr;
        #pragma unroll
        for (int j = 0; j < 4; ++j) {
            lk[TbA + 4 * lg + j][n] = f2bf(acc[0][nj][j]);
            lk[TbB + 4 * lg + j][n] = f2bf(acc[1][nj][j]);
        }
    }
    __syncthreads();                                   // B2

    // ================= v projection =================
    STAGE_W(Wv);
    __syncthreads();                                   // B3
    #pragma unroll
    for (int ti = 0; ti < 2; ++ti)
        #pragma unroll
        for (int nj = 0; nj < 4; ++nj) acc[ti][nj] = (f32x4){0.f,0.f,0.f,0.f};
    #pragma unroll
    for (int ks = 0; ks < 8; ++ks)
        #pragma unroll
        for (int nj = 0; nj < 4; ++nj) {
            short8 bf = *(const short8*)&wt[16 * nj + lr][ks * 32 + lg * 8];
            acc[0][nj] = MFMA32(af[0][ks], bf, acc[0][nj]);
            acc[1][nj] = MFMA32(af[1][ks], bf, acc[1][nj]);
        }
    #pragma unroll
    for (int ti = 0; ti < 2; ++ti) {
        const int s0 = (ti ? TbB : TbA) + 4 * lg;
        #pragma unroll
        for (int nj = 0; nj < 4; ++nj) {
            ushort4v pk;
            pk[0] = f2bf(acc[ti][nj][0]);
            pk[1] = f2bf(acc[ti][nj][1]);
            pk[2] = f2bf(acc[ti][nj][2]);
            pk[3] = f2bf(acc[ti][nj][3]);
            *(ushort4v*)&lvT[16 * nj + lr][s0] = pk;
        }
    }
    __syncthreads();                                   // B4

    // ================= q projection (SWAPPED operands -> q^T frags) =================
    STAGE_W(Wq);
    __syncthreads();                                   // B5 (also: lk/lvT visible)
    #pragma unroll
    for (int ti = 0; ti < 2; ++ti)
        #pragma unroll
        for (int nj = 0; nj < 4; ++nj) acc[ti][nj] = (f32x4){0.f,0.f,0.f,0.f};
    #pragma unroll
    for (int ks = 0; ks < 8; ++ks)
        #pragma unroll
        for (int nj = 0; nj < 4; ++nj) {
            short8 bf = *(const short8*)&wt[16 * nj + lr][ks * 32 + lg * 8];
            acc[0][nj] = MFMA32(bf, af[0][ks], acc[0][nj]);   // A=W^T, B=x
            acc[1][nj] = MFMA32(bf, af[1][ks], acc[1][nj]);
        }
    short8 qf[2][2];
    #pragma unroll
    for (int nj = 0; nj < 4; ++nj)
        #pragma unroll
        for (int j = 0; j < 4; ++j) {
            qf[0][nj >> 1][(nj & 1) * 4 + j] = (short)f2bf(acc[0][nj][j]);
            qf[1][nj >> 1][(nj & 1) * 4 + j] = (short)f2bf(acc[1][nj][j]);
        }

    // ================= attention (barrier-free, waves desync) =================
    float* ob = out + (size_t)b * (256 * 64);
    u16* pbw = &pb[w][0][0];

    do_tile(TbA, nst0, lr, lg, qf[0], lk, lvT, pbw, mb, ob, mA[0], mA[1]);
    do_tile(TbB, nst1, lr, lg, qf[1], lk, lvT, pbw, mb, ob, mB[0], mB[1]);
}

extern "C" void kernel_launch(void* const* d_in, const int* in_sizes, int n_in,
                              void* d_out, int out_size, void* d_ws, size_t ws_size,
                              hipStream_t stream) {
    const float* x  = (const float*)d_in[0];
    const float* Wq = (const float*)d_in[1];
    const float* Wk = (const float*)d_in[2];
    const float* Wv = (const float*)d_in[3];
    const float* dm = (const float*)d_in[4];
    float* outp     = (float*)d_out;
    attn_head_fused<<<dim3(512), dim3(512), 0, stream>>>(x, Wq, Wk, Wv, dm, outp);
}

// Round 9
// 68.629 us; speedup vs baseline: 1.0674x; 1.0674x over previous
//
#include <hip/hip_runtime.h>
#include <hip/hip_bf16.h>

typedef __attribute__((ext_vector_type(8))) short short8;
typedef __attribute__((ext_vector_type(4))) float f32x4;
typedef __attribute__((ext_vector_type(4))) unsigned short ushort4v;
typedef unsigned short u16;

#define MFMA32(a, b, c) __builtin_amdgcn_mfma_f32_16x16x32_bf16((a), (b), (c), 0, 0, 0)

__device__ __forceinline__ u16 f2bf(float f) {
    union { float f; unsigned int u; } v; v.f = f;
    unsigned int r = v.u + 0x7FFFu + ((v.u >> 16) & 1u);   // RNE
    return (u16)(r >> 16);
}

// Rolled flash attention for one 16-row t-tile (R7-verified body).
// NATURAL fragment layouts: qf and kf are straight b128 reads
// (slot i <-> k = 32*ks + 8*lg + i for both A and B operands).
__device__ __forceinline__ void do_tile(int Tb, int nst, int lr, int lg,
                                        const u16 (*lq)[72],
                                        const u16 (*lk)[72],
                                        const u16 (*lvT)[264],
                                        u16* pbw,                   // wave-private [16][40]
                                        const float* mb, float* ob)
{
    const int tb = Tb + 4 * lg;

    // q A-frags from LDS handoff (one-time, natural layout)
    short8 qf0 = *(const short8*)&lq[Tb + lr][lg * 8];
    short8 qf1 = *(const short8*)&lq[Tb + lr][32 + lg * 8];

    float m[4], ls[4];
    f32x4 O[4];
    #pragma unroll
    for (int j = 0; j < 4; ++j) { m[j] = -1e30f; ls[j] = 0.f; }
    #pragma unroll
    for (int ht = 0; ht < 4; ++ht) O[ht] = (f32x4){0.f, 0.f, 0.f, 0.f};

    // dropout masks for chunk 0 (prefetched; consumed late in first iteration)
    float pm[2][4];
    #pragma unroll
    for (int sl = 0; sl < 2; ++sl) {
        #pragma unroll
        for (int j = 0; j < 4; ++j) pm[sl][j] = 0.f;
        if (sl < nst) {
            #pragma unroll
            for (int j = 0; j < 4; ++j)
                pm[sl][j] = mb[(size_t)(tb + j) * 256 + 16 * sl + lr];
        }
    }

    #pragma unroll 1
    for (int c = 0; 2 * c < nst; ++c) {
        // prefetch next chunk's dropout masks (fly under this chunk's compute)
        float nm[2][4];
        #pragma unroll
        for (int sl = 0; sl < 2; ++sl) {
            const int stn = 2 * c + 2 + sl;
            #pragma unroll
            for (int j = 0; j < 4; ++j) nm[sl][j] = 0.f;
            if (stn < nst) {
                #pragma unroll
                for (int j = 0; j < 4; ++j)
                    nm[sl][j] = mb[(size_t)(tb + j) * 256 + 16 * stn + lr];
            }
        }

        // ---- QK^T for s-tiles 2c, 2c+1 (odd tail causally dead; row < 256 always) ----
        f32x4 S[2];
        #pragma unroll
        for (int sl = 0; sl < 2; ++sl) {
            const u16* kr = &lk[16 * (2 * c + sl) + lr][0];
            short8 kf0 = *(const short8*)&kr[8 * lg];
            short8 kf1 = *(const short8*)&kr[32 + 8 * lg];
            f32x4 a = (f32x4){0.f, 0.f, 0.f, 0.f};
            a = MFMA32(qf0, kf0, a);
            a = MFMA32(qf1, kf1, a);
            S[sl] = a;
        }

        // ---- scale + causal mask + chunk max ----
        float cm[4];
        #pragma unroll
        for (int j = 0; j < 4; ++j) cm[j] = m[j];
        #pragma unroll
        for (int sl = 0; sl < 2; ++sl) {
            const int s = 16 * (2 * c + sl) + lr;
            #pragma unroll
            for (int j = 0; j < 4; ++j) {
                float Lv = (s <= tb + j) ? S[sl][j] * 0.125f : -1e30f;
                S[sl][j] = Lv;
                cm[j] = fmaxf(cm[j], Lv);
            }
        }
        #pragma unroll
        for (int d = 1; d < 16; d <<= 1)
            #pragma unroll
            for (int j = 0; j < 4; ++j)
                cm[j] = fmaxf(cm[j], __shfl_xor(cm[j], d, 64));

        // ---- rescale running state (fs == 0 on first chunk since m = -1e30) ----
        float fs[4];
        #pragma unroll
        for (int j = 0; j < 4; ++j)
            fs[j] = exp2f((m[j] - cm[j]) * 1.44269504f);
        {
            float fsel = (lr & 3) == 0 ? fs[0] : (lr & 3) == 1 ? fs[1]
                       : (lr & 3) == 2 ? fs[2] : fs[3];
            float fO = __shfl(fsel, ((lr >> 2) << 4) | lr, 64);
            #pragma unroll
            for (int ht = 0; ht < 4; ++ht) O[ht] *= fO;
        }
        #pragma unroll
        for (int j = 0; j < 4; ++j) m[j] = cm[j];

        // ---- exp + chunk sum ----
        float cs[4] = {0.f, 0.f, 0.f, 0.f};
        #pragma unroll
        for (int sl = 0; sl < 2; ++sl)
            #pragma unroll
            for (int j = 0; j < 4; ++j) {
                float p = exp2f((S[sl][j] - m[j]) * 1.44269504f);
                S[sl][j] = p;
                cs[j] += p;
            }
        #pragma unroll
        for (int d = 1; d < 16; d <<= 1)
            #pragma unroll
            for (int j = 0; j < 4; ++j)
                cs[j] += __shfl_xor(cs[j], d, 64);
        #pragma unroll
        for (int j = 0; j < 4; ++j)
            ls[j] = ls[j] * fs[j] + cs[j];

        // ---- dropout + pack -> wave-private P^T (t-major [16][40]) ----
        #pragma unroll
        for (int sl = 0; sl < 2; ++sl)
            #pragma unroll
            for (int j = 0; j < 4; ++j) {
                float p = (pm[sl][j] >= 0.25f) ? S[sl][j] : 0.f;
                pbw[(4 * lg + j) * 40 + 16 * sl + lr] = f2bf(p);
            }
        asm volatile("s_waitcnt lgkmcnt(0)" ::: "memory");
        __builtin_amdgcn_sched_barrier(0);
        short8 pf = *(const short8*)&pbw[lr * 40 + 8 * lg];
        #pragma unroll
        for (int ht = 0; ht < 4; ++ht) {
            short8 vf = *(const short8*)&lvT[16 * ht + lr][32 * c + 8 * lg];
            O[ht] = MFMA32(vf, pf, O[ht]);
        }
        #pragma unroll
        for (int sl = 0; sl < 2; ++sl)
            #pragma unroll
            for (int j = 0; j < 4; ++j)
                pm[sl][j] = nm[sl][j];
    }

    // ---- final normalize + store ----
    float rs[4];
    #pragma unroll
    for (int j = 0; j < 4; ++j)
        rs[j] = 1.33333333333f / ls[j];     // (1/sum) * 1/(1-0.25)
    float rsel = (lr & 3) == 0 ? rs[0] : (lr & 3) == 1 ? rs[1]
               : (lr & 3) == 2 ? rs[2] : rs[3];
    float rfin = __shfl(rsel, ((lr >> 2) << 4) | lr, 64);
    #pragma unroll
    for (int ht = 0; ht < 4; ++ht) {
        f32x4 o = O[ht] * rfin;
        *(f32x4*)&ob[(size_t)(Tb + lr) * 64 + 16 * ht + 4 * lg] = o;
    }
}

// stage full W^T bf16 into wt with 1024 threads: thread owns row r = tid&63,
// chunks c0 = 8*(tid>>6) and 8*(tid>>6)+128. Global reads coalesced (64
// consecutive floats per instr across the row-dim).
#define STAGE_W(Wm) do {                                                     \
    const int r_ = tid & 63, g_ = tid >> 6;                                  \
    _Pragma("unroll")                                                        \
    for (int i_ = 0; i_ < 2; ++i_) {                                         \
        const int c0_ = 8 * g_ + 128 * i_;                                   \
        short8 t_;                                                           \
        _Pragma("unroll")                                                    \
        for (int j_ = 0; j_ < 8; ++j_)                                       \
            t_[j_] = (short)f2bf((Wm)[(size_t)(c0_ + j_) * 64 + r_]);        \
        *(short8*)&wt[r_][c0_] = t_;                                         \
    } } while (0)

// One 1024-thread workgroup (16 waves) per batch; wave w projects t-tile w.
// Attention: wave w<8 -> tile w (nst=w+1); wave w>=8 -> tile 23-w (nst=24-w).
// Per-SIMD s-tile load = 34, uniform. LDS = 161792 B -> 1 block/CU, 16 waves.
__global__ __launch_bounds__(1024, 4)
void attn_head_fused(const float* __restrict__ x,
                     const float* __restrict__ Wq,
                     const float* __restrict__ Wk,
                     const float* __restrict__ Wv,
                     const float* __restrict__ dmask,
                     float* __restrict__ out)
{
    __shared__ __align__(16) u16 lq[256][72];       // q  [t][h]    36864 B
    __shared__ __align__(16) u16 lk[256][72];       // k  [s][h]    36864 B
    __shared__ __align__(16) u16 lvT[64][264];      // v^T [h][s]   33792 B
    __shared__ __align__(16) u16 wt[64][264];       // W^T [n][c]   33792 B
    __shared__ __align__(16) u16 pb[16][16][40];    // per-wave P^T 20480 B

    const int b   = blockIdx.x;
    const int tid = threadIdx.x;
    const int w   = tid >> 6;      // wave 0..15
    const int l   = tid & 63;
    const int lr  = l & 15;
    const int lg  = l >> 4;

    const int Tb = 16 * w;         // this wave's projection tile

    const float* xb = x + (size_t)b * (256 * 256);
    const float* mb = dmask + (size_t)b * (256 * 256);

    // ---- x A-fragments for this wave's tile (reused by all three projections) ----
    short8 af[8];
    {
        const float* xr = xb + (size_t)(Tb + lr) * 256 + lg * 8;
        #pragma unroll
        for (int ks = 0; ks < 8; ++ks) {
            f32x4 a0 = *(const f32x4*)(xr + ks * 32);
            f32x4 a1 = *(const f32x4*)(xr + ks * 32 + 4);
            short8 f;
            f[0] = (short)f2bf(a0[0]); f[1] = (short)f2bf(a0[1]);
            f[2] = (short)f2bf(a0[2]); f[3] = (short)f2bf(a0[3]);
            f[4] = (short)f2bf(a1[0]); f[5] = (short)f2bf(a1[1]);
            f[6] = (short)f2bf(a1[2]); f[7] = (short)f2bf(a1[3]);
            af[ks] = f;
        }
    }

    f32x4 acc[4];

    // ================= k projection =================
    STAGE_W(Wk);
    __syncthreads();                                   // B1
    #pragma unroll
    for (int nj = 0; nj < 4; ++nj) acc[nj] = (f32x4){0.f,0.f,0.f,0.f};
    #pragma unroll
    for (int ks = 0; ks < 8; ++ks)
        #pragma unroll
        for (int nj = 0; nj < 4; ++nj) {
            short8 bf = *(const short8*)&wt[16 * nj + lr][ks * 32 + lg * 8];
            acc[nj] = MFMA32(af[ks], bf, acc[nj]);
        }
    #pragma unroll
    for (int nj = 0; nj < 4; ++nj) {
        const int n = 16 * nj + lr;
        #pragma unroll
        for (int j = 0; j < 4; ++j)
            lk[Tb + 4 * lg + j][n] = f2bf(acc[nj][j]);
    }
    __syncthreads();                                   // B2 (wt readers done)

    // ================= v projection =================
    STAGE_W(Wv);
    __syncthreads();                                   // B3
    #pragma unroll
    for (int nj = 0; nj < 4; ++nj) acc[nj] = (f32x4){0.f,0.f,0.f,0.f};
    #pragma unroll
    for (int ks = 0; ks < 8; ++ks)
        #pragma unroll
        for (int nj = 0; nj < 4; ++nj) {
            short8 bf = *(const short8*)&wt[16 * nj + lr][ks * 32 + lg * 8];
            acc[nj] = MFMA32(af[ks], bf, acc[nj]);
        }
    {
        const int s0 = Tb + 4 * lg;
        #pragma unroll
        for (int nj = 0; nj < 4; ++nj) {
            ushort4v pk;
            pk[0] = f2bf(acc[nj][0]);
            pk[1] = f2bf(acc[nj][1]);
            pk[2] = f2bf(acc[nj][2]);
            pk[3] = f2bf(acc[nj][3]);
            *(ushort4v*)&lvT[16 * nj + lr][s0] = pk;
        }
    }
    __syncthreads();                                   // B4 (wt readers done)

    // ================= q projection =================
    STAGE_W(Wq);
    __syncthreads();                                   // B5
    #pragma unroll
    for (int nj = 0; nj < 4; ++nj) acc[nj] = (f32x4){0.f,0.f,0.f,0.f};
    #pragma unroll
    for (int ks = 0; ks < 8; ++ks)
        #pragma unroll
        for (int nj = 0; nj < 4; ++nj) {
            short8 bf = *(const short8*)&wt[16 * nj + lr][ks * 32 + lg * 8];
            acc[nj] = MFMA32(af[ks], bf, acc[nj]);
        }
    #pragma unroll
    for (int nj = 0; nj < 4; ++nj) {
        const int n = 16 * nj + lr;
        #pragma unroll
        for (int j = 0; j < 4; ++j)
            lq[Tb + 4 * lg + j][n] = f2bf(acc[nj][j]);
    }
    __syncthreads();                                   // B6: lq/lk/lvT visible

    // ================= attention (16 waves, barrier-free, per-SIMD balanced) =================
    float* ob = out + (size_t)b * (256 * 64);
    const int tile = (w < 8) ? w : 23 - w;
    do_tile(16 * tile, tile + 1, lr, lg, lq, lk, lvT, &pb[w][0][0], mb, ob);
}

extern "C" void kernel_launch(void* const* d_in, const int* in_sizes, int n_in,
                              void* d_out, int out_size, void* d_ws, size_t ws_size,
                              hipStream_t stream) {
    const float* x  = (const float*)d_in[0];
    const float* Wq = (const float*)d_in[1];
    const float* Wk = (const float*)d_in[2];
    const float* Wv = (const float*)d_in[3];
    const float* dm = (const float*)d_in[4];
    float* outp     = (float*)d_out;
    attn_head_fused<<<dim3(512), dim3(1024), 0, stream>>>(x, Wq, Wk, Wv, dm, outp);
}